// Round 18
// baseline (451.291 us; speedup 1.0000x reference)
//
#include <hip/hip_runtime.h>
#include <math.h>

// B=32, Cin=64, H=W=56, Cout=128, K=3 pad=1 -> D=576, out (32,128,56,56) fp32
#define B_    32
#define CIN   64
#define HH    56
#define WW    56
#define COUT  128
#define DD    576
#define KC    384            // OpenBLAS kc split (verified R9)
#define LPX   (HH*WW)        // 3136 = 49*64
#define TOTAL (B_*COUT*LPX)
#define NX    (B_*CIN*LPX)   // 6422528
#define MARGIN 4e-4f         // worst-case split-bf16 + reorder bound (validated R15-17)
#define SENT   2.0f

typedef __attribute__((ext_vector_type(8)))  short  short8;
typedef __attribute__((ext_vector_type(16))) float  float16v;

__device__ __forceinline__ unsigned short bf16_rne(float f) {
    unsigned u = __float_as_uint(f);
    unsigned r = u + 0x7FFFu + ((u >> 16) & 1u);
    return (unsigned short)(r >> 16);
}
__device__ __forceinline__ float bf16_to_f(unsigned short h) {
    return __uint_as_float(((unsigned)h) << 16);
}

// ---- bit-exact numpy FLOAT_sin (npyv FMA path) — verified R9 ----
__device__ __forceinline__ float np_sinf(float x) {
#pragma clang fp contract(off)
    const float rint_cvt = 0x1.8p+23f;
    float q = __fmul_rn(x, 0x1.45f306p-1f);
    q = __fadd_rn(q, rint_cvt);
    q = __fsub_rn(q, rint_cvt);
    float r = fmaf(q, -0x1.921fb0p+0f, x);
    r = fmaf(q, -0x1.5110b4p-22f, r);
    r = fmaf(q, -0x1.846988p-48f, r);
    float r2 = __fmul_rn(r, r);
    float s = fmaf(0x1.7d3bbcp-19f, r2, -0x1.a06bbap-13f);
    s = fmaf(s, r2, 0x1.11119ap-7f);
    s = fmaf(s, r2, -0x1.555556p-3f);
    s = __fmul_rn(s, r2);
    s = fmaf(s, r, r);
    float c = fmaf(0x1.98e616p-16f, r2, -0x1.6c06dcp-10f);
    c = fmaf(c, r2, 0x1.55553cp-5f);
    c = fmaf(c, r2, -0.5f);
    c = fmaf(c, r2, 1.0f);
    int iq = (int)q;
    float res = (iq & 1) ? c : s;
    unsigned sgn = ((unsigned)(iq & 2)) << 30;
    return __uint_as_float(__float_as_uint(res) ^ sgn);
}
__device__ __forceinline__ int dec_np(float z) {
    float s = np_sinf(z);
    return (__fmul_rn(s, s) > 0.5f) ? 1 : 0;
}

// ---- prep: split W -> bf16 hi/lo (+ zero worklist counter); split x ----
__global__ __launch_bounds__(256)
void prep_w(const float* __restrict__ W, unsigned short* __restrict__ Wh,
            unsigned short* __restrict__ Wl, unsigned* __restrict__ wcount) {
    int i = blockIdx.x * 256 + threadIdx.x;
    if (i == 0) *wcount = 0;
    if (i >= COUT * DD) return;
    float w = W[i];
    unsigned short h = bf16_rne(w);
    Wh[i] = h;
    Wl[i] = bf16_rne(w - bf16_to_f(h));
}
__global__ __launch_bounds__(256)
void prep_x(const float* __restrict__ x, unsigned* __restrict__ xs) {
    int i = blockIdx.x * 256 + threadIdx.x;
    if (i >= NX) return;
    float f = x[i];
    unsigned short h = bf16_rne(f);
    unsigned short l = bf16_rne(f - bf16_to_f(h));
    xs[i] = (unsigned)h | ((unsigned)l << 16);
}

// ---- MFMA conv: block = 128 o x 64 px, 4 waves (64o x 32px each) ----
// grid 49x32=1568 blocks, LDS 24KB. Fragment-major LDS; pre-split x gathers.
// Borderline elements appended to worklist (direct atomicAdd; ~6K total hits).
#define FRAG(t, s, hf, ln)  (((t) * 1024) + ((s) * 512) + ((hf) * 256) + ((ln) * 8))
__global__ __launch_bounds__(256, 4)
void conv_mfma(const unsigned* __restrict__ xs,
               const unsigned short* __restrict__ Whg,
               const unsigned short* __restrict__ Wlg,
               const float* __restrict__ bias,
               float* __restrict__ out,
               unsigned* __restrict__ wcount,
               unsigned* __restrict__ wlist,
               unsigned wcap) {
    __shared__ __align__(16) unsigned short sWh[4096];   // 8 KB
    __shared__ __align__(16) unsigned short sWl[4096];   // 8 KB
    __shared__ __align__(16) unsigned short sPh[2048];   // 4 KB
    __shared__ __align__(16) unsigned short sPl[2048];   // 4 KB

    const int tid = threadIdx.x;
    const int pt0 = blockIdx.x * 64;     // px tile base (49*64=3136: exact)
    const int b   = blockIdx.y;

    // staging ids
    const int plane = tid & 15;          // px lane -> coalesced gathers
    const int pair  = tid >> 4;          // d-pair 0..15
    const int s_st  = pair >> 3;
    const int h_st  = (pair >> 2) & 1;
    const int j2_st = pair & 3;
    int ypx[4], xpx[4];
#pragma unroll
    for (int r = 0; r < 4; ++r) {
        int pxg = pt0 + plane + r * 16;
        ypx[r] = pxg / WW;
        xpx[r] = pxg - ypx[r] * WW;
    }
    const unsigned* xb = xs + (size_t)b * CIN * LPX;
    const int wo  = tid >> 1;            // W staging: o 0..127
    const int whf = tid & 1;
    const int wot = wo >> 5, wom = wo & 31;

    // compute ids
    const int w    = tid >> 6;           // wave 0..3
    const int lane = tid & 63;
    const int lm   = lane & 31;
    const int half = lane >> 5;
    const int aw   = w >> 1;             // o half (0..1)
    const int nw   = w & 1;              // px tile (0..1)

    float16v acc[2];
#pragma unroll
    for (int a = 0; a < 2; ++a)
#pragma unroll
        for (int i = 0; i < 16; ++i) acc[a][i] = 0.f;

    for (int k0 = 0; k0 < DD; k0 += 32) {
        __syncthreads();
        // stage W hi/lo (fragment-major)
        {
            const uint4* sh = (const uint4*)(Whg + (size_t)wo * DD + k0 + whf * 16);
            const uint4* sl = (const uint4*)(Wlg + (size_t)wo * DD + k0 + whf * 16);
            uint4 h0 = sh[0], h1 = sh[1];
            uint4 l0 = sl[0], l1 = sl[1];
            *(uint4*)(sWh + FRAG(wot, whf, 0, wom)) = h0;
            *(uint4*)(sWh + FRAG(wot, whf, 1, wom)) = h1;
            *(uint4*)(sWl + FRAG(wot, whf, 0, wom)) = l0;
            *(uint4*)(sWl + FRAG(wot, whf, 1, wom)) = l1;
        }
        // stage P hi/lo: u32 gathers of pre-split x, perm-pack, b32 writes
        {
            int d0 = k0 + pair * 2;
            int c0 = d0 / 9, t0 = d0 - c0 * 9;
            int u0 = t0 / 3, v0 = t0 - u0 * 3;
            int t1 = t0 + 1, c1 = c0;
            if (t1 == 9) { t1 = 0; c1 = c0 + 1; }
            int u1 = t1 / 3, v1 = t1 - u1 * 3;
            int base0 = c0 * LPX + (u0 - 1) * WW + (v0 - 1);
            int base1 = c1 * LPX + (u1 - 1) * WW + (v1 - 1);
#pragma unroll
            for (int r = 0; r < 4; ++r) {
                int gy0 = ypx[r] + u0 - 1, gx0 = xpx[r] + v0 - 1;
                int gy1 = ypx[r] + u1 - 1, gx1 = xpx[r] + v1 - 1;
                int pxoff = ypx[r] * WW + xpx[r];
                unsigned g0 = ((unsigned)gy0 < HH && (unsigned)gx0 < WW)
                                  ? xb[base0 + pxoff] : 0u;
                unsigned g1 = ((unsigned)gy1 < HH && (unsigned)gx1 < WW)
                                  ? xb[base1 + pxoff] : 0u;
                unsigned hw = (g0 & 0xFFFFu) | (g1 << 16);          // h0|h1
                unsigned lw = (g0 >> 16) | (g1 & 0xFFFF0000u);      // l0|l1
                int pm = plane + (r & 1) * 16;
                int word = (r >> 1) * 512 + s_st * 256 + h_st * 128 + pm * 4 + j2_st;
                ((unsigned*)sPh)[word] = hw;
                ((unsigned*)sPl)[word] = lw;
            }
        }
        __syncthreads();
#pragma unroll
        for (int s = 0; s < 2; ++s) {
            short8 Ah[2], Al[2], Bh, Bl;
#pragma unroll
            for (int a = 0; a < 2; ++a) {
                int ot = aw * 2 + a;
                Ah[a] = *(const short8*)(sWh + FRAG(ot, s, half, lm));
                Al[a] = *(const short8*)(sWl + FRAG(ot, s, half, lm));
            }
            Bh = *(const short8*)(sPh + FRAG(nw, s, half, lm));
            Bl = *(const short8*)(sPl + FRAG(nw, s, half, lm));
#pragma unroll
            for (int a = 0; a < 2; ++a)
                acc[a] = __builtin_amdgcn_mfma_f32_32x32x16_bf16(Ah[a], Bh, acc[a], 0, 0, 0);
#pragma unroll
            for (int a = 0; a < 2; ++a)
                acc[a] = __builtin_amdgcn_mfma_f32_32x32x16_bf16(Ah[a], Bl, acc[a], 0, 0, 0);
#pragma unroll
            for (int a = 0; a < 2; ++a)
                acc[a] = __builtin_amdgcn_mfma_f32_32x32x16_bf16(Al[a], Bh, acc[a], 0, 0, 0);
        }
    }

    // epilogue: bias + parity decision; borderline -> worklist (rare)
    const size_t outb = (size_t)b * COUT * LPX;
    const int pxg = pt0 + nw * 32 + lm;
#pragma unroll
    for (int a = 0; a < 2; ++a) {
        const int obase = aw * 64 + a * 32 + 4 * half;
#pragma unroll
        for (int reg = 0; reg < 16; ++reg) {
            int o = obase + (reg & 3) + 8 * (reg >> 2);
            float z = acc[a][reg] + bias[o];
            float q = rintf(__fmul_rn(z, 0.63661975f));
            float rr = fmaf(q, -1.5707964f, z);
            float d = fabsf(fabsf(rr) - 0.78539816f);
            size_t oidx = outb + (size_t)o * LPX + pxg;
            out[oidx] = (float)(((int)q) & 1);
            if (d < MARGIN) {                       // ~5e-4 of elements
                unsigned pos = atomicAdd(wcount, 1u);
                if (pos < wcap) wlist[pos] = (unsigned)oidx;
            }
        }
    }
}

// ---- worklist fixup: bit-exact replay of verified R9 path ----
__global__ __launch_bounds__(256)
void exact_fix(const float* __restrict__ x,
               const float* __restrict__ Wt,
               const float* __restrict__ bias,
               float* __restrict__ out,
               const unsigned* __restrict__ wcount,
               const unsigned* __restrict__ wlist,
               unsigned wcap) {
#pragma clang fp contract(off)
    unsigned n = *wcount;
    if (n > wcap) n = wcap;
    for (unsigned k = blockIdx.x * 256 + threadIdx.x; k < n; k += gridDim.x * 256) {
        unsigned idx = wlist[k];
        int px = idx % WW;
        unsigned t = idx / WW;
        int py = t % HH;  t /= HH;
        int o  = t % COUT;
        int b  = t / COUT;
        const float* wrow = Wt + (size_t)o * DD;
        const float* xb   = x + (size_t)b * CIN * LPX;
        int  voff[9];
        bool vok[9];
#pragma unroll
        for (int u = 0; u < 3; ++u)
#pragma unroll
            for (int v = 0; v < 3; ++v) {
                int gy = py + u - 1, gx = px + v - 1;
                vok[u * 3 + v]  = ((unsigned)gy < HH) && ((unsigned)gx < WW);
                voff[u * 3 + v] = gy * WW + gx;
            }
        float accA = 0.f, accB2 = 0.f;    // kc=384-split sequential FMA chains
        for (int c = 0; c < CIN; ++c) {
            const float* xc = xb + c * LPX;
            const float* wc = wrow + c * 9;
            int dbase = c * 9;
#pragma unroll
            for (int tp = 0; tp < 9; ++tp) {
                float p = vok[tp] ? xc[voff[tp]] : 0.f;
                float wv = wc[tp];
                if (dbase + tp < KC) accA  = fmaf(p, wv, accA);
                else                 accB2 = fmaf(p, wv, accB2);
            }
        }
        float zG = __fadd_rn(accA, accB2);
        float z  = __fadd_rn(zG, bias[o]);
        out[idx] = (float)dec_np(z);
    }
}

// ---- fallback (verified R9 path) ----
__global__ __launch_bounds__(256)
void np_emul_conv(const float* __restrict__ x,
                  const float* __restrict__ Wt,
                  const float* __restrict__ bias,
                  float* __restrict__ out) {
#pragma clang fp contract(off)
    int idx = blockIdx.x * 256 + threadIdx.x;
    if (idx >= TOTAL) return;
    int px = idx % WW;
    int t  = idx / WW;
    int py = t % HH;  t /= HH;
    int o  = t % COUT;
    int b  = t / COUT;
    const float* wrow = Wt + (size_t)o * DD;
    const float* xb   = x + (size_t)b * CIN * LPX;
    float accA = 0.f, accB2 = 0.f;
    for (int c = 0; c < CIN; ++c) {
        const float* xc = xb + c * LPX;
        const float* wc = wrow + c * 9;
        int dbase = c * 9;
#pragma unroll
        for (int u = 0; u < 3; ++u)
#pragma unroll
            for (int v = 0; v < 3; ++v) {
                int tp = u * 3 + v;
                int gy = py + u - 1, gx = px + v - 1;
                float p = ((unsigned)gy < HH && (unsigned)gx < WW) ? xc[gy * WW + gx] : 0.f;
                if (dbase + tp < KC) accA  = fmaf(p, wc[tp], accA);
                else                 accB2 = fmaf(p, wc[tp], accB2);
            }
    }
    float z = __fadd_rn(__fadd_rn(accA, accB2), bias[o]);
    out[idx] = (float)dec_np(z);
}

extern "C" void kernel_launch(void* const* d_in, const int* in_sizes, int n_in,
                              void* d_out, int out_size, void* d_ws, size_t ws_size,
                              hipStream_t stream) {
    const float* x  = (const float*)d_in[0];
    const float* Wt = (const float*)d_in[1];
    const float* bb = (const float*)d_in[2];
    float* out = (float*)d_out;

    const size_t WSPLIT = (size_t)COUT * DD * 2;          // 147456 B each
    const size_t XS     = (size_t)NX * 4;                 // 25.7 MB
    const size_t FIXED  = 2 * WSPLIT + XS + 4;

    if (ws_size >= FIXED + 65536) {                       // tier A
        unsigned short* Whg = (unsigned short*)d_ws;
        unsigned short* Wlg = Whg + COUT * DD;
        unsigned* xsv    = (unsigned*)((char*)d_ws + 2 * WSPLIT);
        unsigned* wcount = (unsigned*)((char*)d_ws + 2 * WSPLIT + XS);
        unsigned* wlist  = wcount + 1;
        size_t avail = (ws_size - FIXED) / 4;
        unsigned wcap = (avail > 2000000u) ? 2000000u : (unsigned)avail;

        prep_w<<<dim3((COUT * DD + 255) / 256), dim3(256), 0, stream>>>(Wt, Whg, Wlg, wcount);
        prep_x<<<dim3((NX + 255) / 256), dim3(256), 0, stream>>>(x, xsv);
        conv_mfma<<<dim3(49, B_), dim3(256), 0, stream>>>(xsv, Whg, Wlg, bb, out,
                                                          wcount, wlist, wcap);
        exact_fix<<<dim3(64), dim3(256), 0, stream>>>(x, Wt, bb, out,
                                                      wcount, wlist, wcap);
    } else {                                              // tier C: verified naive
        np_emul_conv<<<(TOTAL + 255) / 256, 256, 0, stream>>>(x, Wt, bb, out);
    }
}

// Round 19
// 269.682 us; speedup vs baseline: 1.6734x; 1.6734x over previous
//
#include <hip/hip_runtime.h>
#include <math.h>

// B=32, Cin=64, H=W=56, Cout=128, K=3 pad=1 -> D=576, out (32,128,56,56) fp32
#define B_    32
#define CIN   64
#define HH    56
#define WW    56
#define COUT  128
#define DD    576
#define KC    384            // OpenBLAS kc split (verified R9)
#define LPX   (HH*WW)        // 3136 = 49*64
#define TOTAL (B_*COUT*LPX)
#define NX    (B_*CIN*LPX)   // 6422528
#define MARGIN 4e-4f         // worst-case split-bf16 + reorder bound (validated R15-18)

typedef __attribute__((ext_vector_type(8)))  short  short8;
typedef __attribute__((ext_vector_type(16))) float  float16v;

__device__ __forceinline__ unsigned short bf16_rne(float f) {
    unsigned u = __float_as_uint(f);
    unsigned r = u + 0x7FFFu + ((u >> 16) & 1u);
    return (unsigned short)(r >> 16);
}
__device__ __forceinline__ float bf16_to_f(unsigned short h) {
    return __uint_as_float(((unsigned)h) << 16);
}

// ---- bit-exact numpy FLOAT_sin (npyv FMA path) — verified R9 ----
__device__ __forceinline__ float np_sinf(float x) {
#pragma clang fp contract(off)
    const float rint_cvt = 0x1.8p+23f;
    float q = __fmul_rn(x, 0x1.45f306p-1f);
    q = __fadd_rn(q, rint_cvt);
    q = __fsub_rn(q, rint_cvt);
    float r = fmaf(q, -0x1.921fb0p+0f, x);
    r = fmaf(q, -0x1.5110b4p-22f, r);
    r = fmaf(q, -0x1.846988p-48f, r);
    float r2 = __fmul_rn(r, r);
    float s = fmaf(0x1.7d3bbcp-19f, r2, -0x1.a06bbap-13f);
    s = fmaf(s, r2, 0x1.11119ap-7f);
    s = fmaf(s, r2, -0x1.555556p-3f);
    s = __fmul_rn(s, r2);
    s = fmaf(s, r, r);
    float c = fmaf(0x1.98e616p-16f, r2, -0x1.6c06dcp-10f);
    c = fmaf(c, r2, 0x1.55553cp-5f);
    c = fmaf(c, r2, -0.5f);
    c = fmaf(c, r2, 1.0f);
    int iq = (int)q;
    float res = (iq & 1) ? c : s;
    unsigned sgn = ((unsigned)(iq & 2)) << 30;
    return __uint_as_float(__float_as_uint(res) ^ sgn);
}
__device__ __forceinline__ int dec_np(float z) {
    float s = np_sinf(z);
    return (__fmul_rn(s, s) > 0.5f) ? 1 : 0;
}

// ---- prep: split W -> bf16 hi/lo (+ zero worklist counter); split x ----
__global__ __launch_bounds__(256)
void prep_w(const float* __restrict__ W, unsigned short* __restrict__ Wh,
            unsigned short* __restrict__ Wl, unsigned* __restrict__ wcount) {
    int i = blockIdx.x * 256 + threadIdx.x;
    if (i == 0) *wcount = 0;
    if (i >= COUT * DD) return;
    float w = W[i];
    unsigned short h = bf16_rne(w);
    Wh[i] = h;
    Wl[i] = bf16_rne(w - bf16_to_f(h));
}
__global__ __launch_bounds__(256)
void prep_x(const float* __restrict__ x, unsigned* __restrict__ xs) {
    int i = blockIdx.x * 256 + threadIdx.x;
    if (i >= NX) return;
    float f = x[i];
    unsigned short h = bf16_rne(f);
    unsigned short l = bf16_rne(f - bf16_to_f(h));
    xs[i] = (unsigned)h | ((unsigned)l << 16);
}

// ---- MFMA conv (unchanged from R17/R18 verified path) ----
#define FRAG(t, s, hf, ln)  (((t) * 1024) + ((s) * 512) + ((hf) * 256) + ((ln) * 8))
__global__ __launch_bounds__(256, 4)
void conv_mfma(const unsigned* __restrict__ xs,
               const unsigned short* __restrict__ Whg,
               const unsigned short* __restrict__ Wlg,
               const float* __restrict__ bias,
               float* __restrict__ out,
               unsigned* __restrict__ wcount,
               unsigned* __restrict__ wlist,
               unsigned wcap) {
    __shared__ __align__(16) unsigned short sWh[4096];
    __shared__ __align__(16) unsigned short sWl[4096];
    __shared__ __align__(16) unsigned short sPh[2048];
    __shared__ __align__(16) unsigned short sPl[2048];

    const int tid = threadIdx.x;
    const int pt0 = blockIdx.x * 64;
    const int b   = blockIdx.y;

    const int plane = tid & 15;
    const int pair  = tid >> 4;
    const int s_st  = pair >> 3;
    const int h_st  = (pair >> 2) & 1;
    const int j2_st = pair & 3;
    int ypx[4], xpx[4];
#pragma unroll
    for (int r = 0; r < 4; ++r) {
        int pxg = pt0 + plane + r * 16;
        ypx[r] = pxg / WW;
        xpx[r] = pxg - ypx[r] * WW;
    }
    const unsigned* xb = xs + (size_t)b * CIN * LPX;
    const int wo  = tid >> 1;
    const int whf = tid & 1;
    const int wot = wo >> 5, wom = wo & 31;

    const int w    = tid >> 6;
    const int lane = tid & 63;
    const int lm   = lane & 31;
    const int half = lane >> 5;
    const int aw   = w >> 1;
    const int nw   = w & 1;

    float16v acc[2];
#pragma unroll
    for (int a = 0; a < 2; ++a)
#pragma unroll
        for (int i = 0; i < 16; ++i) acc[a][i] = 0.f;

    for (int k0 = 0; k0 < DD; k0 += 32) {
        __syncthreads();
        {
            const uint4* sh = (const uint4*)(Whg + (size_t)wo * DD + k0 + whf * 16);
            const uint4* sl = (const uint4*)(Wlg + (size_t)wo * DD + k0 + whf * 16);
            uint4 h0 = sh[0], h1 = sh[1];
            uint4 l0 = sl[0], l1 = sl[1];
            *(uint4*)(sWh + FRAG(wot, whf, 0, wom)) = h0;
            *(uint4*)(sWh + FRAG(wot, whf, 1, wom)) = h1;
            *(uint4*)(sWl + FRAG(wot, whf, 0, wom)) = l0;
            *(uint4*)(sWl + FRAG(wot, whf, 1, wom)) = l1;
        }
        {
            int d0 = k0 + pair * 2;
            int c0 = d0 / 9, t0 = d0 - c0 * 9;
            int u0 = t0 / 3, v0 = t0 - u0 * 3;
            int t1 = t0 + 1, c1 = c0;
            if (t1 == 9) { t1 = 0; c1 = c0 + 1; }
            int u1 = t1 / 3, v1 = t1 - u1 * 3;
            int base0 = c0 * LPX + (u0 - 1) * WW + (v0 - 1);
            int base1 = c1 * LPX + (u1 - 1) * WW + (v1 - 1);
#pragma unroll
            for (int r = 0; r < 4; ++r) {
                int gy0 = ypx[r] + u0 - 1, gx0 = xpx[r] + v0 - 1;
                int gy1 = ypx[r] + u1 - 1, gx1 = xpx[r] + v1 - 1;
                int pxoff = ypx[r] * WW + xpx[r];
                unsigned g0 = ((unsigned)gy0 < HH && (unsigned)gx0 < WW)
                                  ? xb[base0 + pxoff] : 0u;
                unsigned g1 = ((unsigned)gy1 < HH && (unsigned)gx1 < WW)
                                  ? xb[base1 + pxoff] : 0u;
                unsigned hw = (g0 & 0xFFFFu) | (g1 << 16);
                unsigned lw = (g0 >> 16) | (g1 & 0xFFFF0000u);
                int pm = plane + (r & 1) * 16;
                int word = (r >> 1) * 512 + s_st * 256 + h_st * 128 + pm * 4 + j2_st;
                ((unsigned*)sPh)[word] = hw;
                ((unsigned*)sPl)[word] = lw;
            }
        }
        __syncthreads();
#pragma unroll
        for (int s = 0; s < 2; ++s) {
            short8 Ah[2], Al[2], Bh, Bl;
#pragma unroll
            for (int a = 0; a < 2; ++a) {
                int ot = aw * 2 + a;
                Ah[a] = *(const short8*)(sWh + FRAG(ot, s, half, lm));
                Al[a] = *(const short8*)(sWl + FRAG(ot, s, half, lm));
            }
            Bh = *(const short8*)(sPh + FRAG(nw, s, half, lm));
            Bl = *(const short8*)(sPl + FRAG(nw, s, half, lm));
#pragma unroll
            for (int a = 0; a < 2; ++a)
                acc[a] = __builtin_amdgcn_mfma_f32_32x32x16_bf16(Ah[a], Bh, acc[a], 0, 0, 0);
#pragma unroll
            for (int a = 0; a < 2; ++a)
                acc[a] = __builtin_amdgcn_mfma_f32_32x32x16_bf16(Ah[a], Bl, acc[a], 0, 0, 0);
#pragma unroll
            for (int a = 0; a < 2; ++a)
                acc[a] = __builtin_amdgcn_mfma_f32_32x32x16_bf16(Al[a], Bh, acc[a], 0, 0, 0);
        }
    }

    const size_t outb = (size_t)b * COUT * LPX;
    const int pxg = pt0 + nw * 32 + lm;
#pragma unroll
    for (int a = 0; a < 2; ++a) {
        const int obase = aw * 64 + a * 32 + 4 * half;
#pragma unroll
        for (int reg = 0; reg < 16; ++reg) {
            int o = obase + (reg & 3) + 8 * (reg >> 2);
            float z = acc[a][reg] + bias[o];
            float q = rintf(__fmul_rn(z, 0.63661975f));
            float rr = fmaf(q, -1.5707964f, z);
            float d = fabsf(fabsf(rr) - 0.78539816f);
            size_t oidx = outb + (size_t)o * LPX + pxg;
            out[oidx] = (float)(((int)q) & 1);
            if (d < MARGIN) {
                unsigned pos = atomicAdd(wcount, 1u);
                if (pos < wcap) wlist[pos] = (unsigned)oidx;
            }
        }
    }
}

// ---- wave-cooperative fixup: 1 wave per 4 elements. Lanes gather (parallel,
// BW-bound); lanes 0-3 run the bit-exact kc=384-split serial FMA chain from
// LDS (order identical to R9 -> bit-identical z). ----
__global__ __launch_bounds__(64)
void exact_fix_wave(const float* __restrict__ x,
                    const float* __restrict__ Wt,
                    const float* __restrict__ bias,
                    float* __restrict__ out,
                    const unsigned* __restrict__ wcount,
                    const unsigned* __restrict__ wlist,
                    unsigned wcap) {
#pragma clang fp contract(off)
    __shared__ float sx[4][DD];
    __shared__ float sw[4][DD];
    const int lane = threadIdx.x;        // block = 1 wave
    unsigned n = *wcount;
    if (n > wcap) n = wcap;

    for (unsigned e0 = blockIdx.x * 4; e0 < n; e0 += gridDim.x * 4) {
        // gather 4 elements: lane = channel c
        unsigned idxs[4];
#pragma unroll
        for (int j = 0; j < 4; ++j) {
            unsigned e = e0 + j;
            if (e >= n) { idxs[j] = 0xFFFFFFFFu; continue; }
            unsigned idx = wlist[e];
            idxs[j] = idx;
            int px = idx % WW;
            unsigned t = idx / WW;
            int py = t % HH;  t /= HH;
            int o  = t % COUT;
            int b  = t / COUT;
            const float* xc = x  + ((size_t)(b * CIN + lane)) * LPX;
            const float* wc = Wt + (size_t)o * DD + lane * 9;
#pragma unroll
            for (int u = 0; u < 3; ++u)
#pragma unroll
                for (int v = 0; v < 3; ++v) {
                    int tp = u * 3 + v;
                    int gy = py + u - 1, gx = px + v - 1;
                    float p = ((unsigned)gy < HH && (unsigned)gx < WW)
                                  ? xc[gy * WW + gx] : 0.f;
                    sx[j][lane * 9 + tp] = p;
                    sw[j][lane * 9 + tp] = wc[tp];
                }
        }
        __syncthreads();
        if (lane < 4 && idxs[lane] != 0xFFFFFFFFu) {
            const float* px_ = sx[lane];
            const float* pw_ = sw[lane];
            float accA = 0.f, accB2 = 0.f;
            for (int d = 0; d < KC; ++d)        accA  = fmaf(px_[d], pw_[d], accA);
            for (int d = KC; d < DD; ++d)       accB2 = fmaf(px_[d], pw_[d], accB2);
            unsigned idx = idxs[lane];
            int o = (idx / LPX) % COUT;
            float zG = __fadd_rn(accA, accB2);
            float z  = __fadd_rn(zG, bias[o]);
            out[idx] = (float)dec_np(z);
        }
        __syncthreads();
    }
}

// ---- fallback (verified R9 path) ----
__global__ __launch_bounds__(256)
void np_emul_conv(const float* __restrict__ x,
                  const float* __restrict__ Wt,
                  const float* __restrict__ bias,
                  float* __restrict__ out) {
#pragma clang fp contract(off)
    int idx = blockIdx.x * 256 + threadIdx.x;
    if (idx >= TOTAL) return;
    int px = idx % WW;
    int t  = idx / WW;
    int py = t % HH;  t /= HH;
    int o  = t % COUT;
    int b  = t / COUT;
    const float* wrow = Wt + (size_t)o * DD;
    const float* xb   = x + (size_t)b * CIN * LPX;
    float accA = 0.f, accB2 = 0.f;
    for (int c = 0; c < CIN; ++c) {
        const float* xc = xb + c * LPX;
        const float* wc = wrow + c * 9;
        int dbase = c * 9;
#pragma unroll
        for (int u = 0; u < 3; ++u)
#pragma unroll
            for (int v = 0; v < 3; ++v) {
                int tp = u * 3 + v;
                int gy = py + u - 1, gx = px + v - 1;
                float p = ((unsigned)gy < HH && (unsigned)gx < WW) ? xc[gy * WW + gx] : 0.f;
                if (dbase + tp < KC) accA  = fmaf(p, wc[tp], accA);
                else                 accB2 = fmaf(p, wc[tp], accB2);
            }
    }
    float z = __fadd_rn(__fadd_rn(accA, accB2), bias[o]);
    out[idx] = (float)dec_np(z);
}

extern "C" void kernel_launch(void* const* d_in, const int* in_sizes, int n_in,
                              void* d_out, int out_size, void* d_ws, size_t ws_size,
                              hipStream_t stream) {
    const float* x  = (const float*)d_in[0];
    const float* Wt = (const float*)d_in[1];
    const float* bb = (const float*)d_in[2];
    float* out = (float*)d_out;

    const size_t WSPLIT = (size_t)COUT * DD * 2;          // 147456 B each
    const size_t XS     = (size_t)NX * 4;                 // 25.7 MB
    const size_t FIXED  = 2 * WSPLIT + XS + 4;

    if (ws_size >= FIXED + 65536) {
        unsigned short* Whg = (unsigned short*)d_ws;
        unsigned short* Wlg = Whg + COUT * DD;
        unsigned* xsv    = (unsigned*)((char*)d_ws + 2 * WSPLIT);
        unsigned* wcount = (unsigned*)((char*)d_ws + 2 * WSPLIT + XS);
        unsigned* wlist  = wcount + 1;
        size_t avail = (ws_size - FIXED) / 4;
        unsigned wcap = (avail > 2000000u) ? 2000000u : (unsigned)avail;

        prep_w<<<dim3((COUT * DD + 255) / 256), dim3(256), 0, stream>>>(Wt, Whg, Wlg, wcount);
        prep_x<<<dim3((NX + 255) / 256), dim3(256), 0, stream>>>(x, xsv);
        conv_mfma<<<dim3(49, B_), dim3(256), 0, stream>>>(xsv, Whg, Wlg, bb, out,
                                                          wcount, wlist, wcap);
        exact_fix_wave<<<dim3(1024), dim3(64), 0, stream>>>(x, Wt, bb, out,
                                                            wcount, wlist, wcap);
    } else {
        np_emul_conv<<<(TOTAL + 255) / 256, 256, 0, stream>>>(x, Wt, bb, out);
    }
}